// Round 4
// baseline (81.072 us; speedup 1.0000x reference)
//
#include <hip/hip_runtime.h>
#include <math.h>

typedef __attribute__((ext_vector_type(8))) short short8;
typedef __attribute__((ext_vector_type(4))) float f32x4;
typedef __attribute__((ext_vector_type(2))) int v2i_t;
typedef unsigned short ushort_t;
typedef unsigned int uint_t;

#define HH 128
#define WW 128
#define CC 64
#define HWp 16384

__device__ inline ushort_t f2bf(float f) {
    uint_t u = __float_as_uint(f);
    uint_t r = (u + 0x7FFFu + ((u >> 16) & 1u)) >> 16;
    return (ushort_t)r;
}
__device__ inline float bf2f(ushort_t u) {
    return __uint_as_float(((uint_t)u) << 16);
}
__device__ inline float blo(int u) { return __uint_as_float(((uint_t)u) << 16); }
__device__ inline float bhi(int u) { return __uint_as_float(((uint_t)u) & 0xFFFF0000u); }
__device__ inline short8 bc8(uint4 v) { return __builtin_bit_cast(short8, v); }

// ---------------- weight packing into MFMA A-fragment order -----------------
__global__ __launch_bounds__(256) void k_pack(const float* __restrict__ w_off,
        const float* __restrict__ w_mask, const float* __restrict__ w,
        ushort_t* __restrict__ wpom, ushort_t* __restrict__ wpm) {
    int idx = blockIdx.x * 256 + threadIdx.x;
    if (idx < 18432) {
        int e = idx;
        int j = e & 7, l = (e >> 3) & 63, mf = (e >> 9) & 1, ks = e >> 10;
        int ch = mf * 16 + (l & 15);
        int k = ks * 32 + ((l >> 4) << 3) + j;
        int c = k & 63, kk = k >> 6;
        float v = 0.f;
        if (ch < 18) v = w_off[(ch * CC + c) * 9 + kk];
        else if (ch < 27) v = w_mask[((ch - 18) * CC + c) * 9 + kk];
        wpom[idx] = f2bf(v);
    } else if (idx < 18432 + 36864) {
        int e = idx - 18432;
        int j = e & 7, l = (e >> 3) & 63, mf = (e >> 9) & 3, ks = e >> 11;
        int o = mf * 16 + (l & 15);
        int k = ks * 32 + ((l >> 4) << 3) + j;
        int c = k & 63, kk = k >> 6;
        wpm[e] = f2bf(w[(o * CC + c) * 9 + kk]);
    }
}

// ---------------- x: NCHW f32 -> NHWC bf16 ----------------------------------
__global__ __launch_bounds__(256) void k_transpose_x(const float* __restrict__ x,
                                                     ushort_t* __restrict__ xtb) {
    __shared__ float tile[64][65];
    int bid = blockIdx.x;
    int xs = (bid & 1) * 64;
    int y  = (bid >> 1) & 127;
    int b  = bid >> 8;
    int t = threadIdx.x, lane = t & 63, g = t >> 6;
#pragma unroll
    for (int i = 0; i < 16; ++i) {
        int c = i * 4 + g;
        tile[c][lane] = x[(((size_t)b * CC + c) * HH + y) * WW + xs + lane];
    }
    __syncthreads();
#pragma unroll
    for (int i = 0; i < 16; ++i) {
        int xx = i * 4 + g;
        xtb[(((size_t)b * HH + y) * WW + xs + xx) * CC + lane] = f2bf(tile[lane][xx]);
    }
}

// ---------------- offset/mask conv as MFMA GEMM (512 thr, 8 waves) ----------
__global__ __launch_bounds__(512, 6) void k_conv_om(const ushort_t* __restrict__ xtb,
        const uint4* __restrict__ wpom, const float* __restrict__ b_off,
        const float* __restrict__ b_mask, float* __restrict__ om) {
    __shared__ ushort_t xrow[3 * 132 * 64];   // idx ^= (col&7)<<3 swizzle
    int blk = blockIdx.x;
    int y = blk & 127, b = blk >> 7;
    int t = threadIdx.x;

    for (int ky = 0; ky < 3; ++ky) {
        int yy = y + ky - 1;
        bool ok = (yy >= 0) && (yy < HH);
#pragma unroll
        for (int i = 0; i < 2; ++i) {
            int t2 = i * 512 + t;
            int colr = t2 >> 3;
            int c0 = (t2 & 7) * 8;
            uint4 v = make_uint4(0u, 0u, 0u, 0u);
            if (ok) v = *(const uint4*)&xtb[(((size_t)b * HWp) + yy * WW + colr) * CC + c0];
            int col = colr + 1;
            int idx = ((ky * 132 + col) * 64 + c0) ^ ((col & 7) << 3);
            *(uint4*)&xrow[idx] = v;
        }
    }
    if (t < 48) {
        int ky = t >> 4, cs = (t >> 3) & 1, chn = t & 7;
        int col = cs ? 129 : 0;
        int idx = ((ky * 132 + col) * 64 + chn * 8) ^ ((col & 7) << 3);
        *(uint4*)&xrow[idx] = make_uint4(0u, 0u, 0u, 0u);
    }
    __syncthreads();

    int lane = t & 63, w = t >> 6;
    int lm = lane & 15, lg = lane >> 4;
    int px = w * 16 + lm;
    f32x4 acc[2] = {};
#pragma unroll
    for (int ks = 0; ks < 18; ++ks) {
        int kk = ks >> 1;
        int kyy = kk / 3, kxx = kk % 3;
        int c0 = (ks & 1) * 32 + lg * 8;
        short8 a0 = bc8(wpom[(ks * 2 + 0) * 64 + lane]);
        short8 a1 = bc8(wpom[(ks * 2 + 1) * 64 + lane]);
        int col = px + kxx;
        int idx = ((kyy * 132 + col) * 64 + c0) ^ ((col & 7) << 3);
        short8 bf = *(const short8*)&xrow[idx];
        acc[0] = __builtin_amdgcn_mfma_f32_16x16x32_bf16(a0, bf, acc[0], 0, 0, 0);
        acc[1] = __builtin_amdgcn_mfma_f32_16x16x32_bf16(a1, bf, acc[1], 0, 0, 0);
    }
#pragma unroll
    for (int mf = 0; mf < 2; ++mf)
#pragma unroll
        for (int r = 0; r < 4; ++r) {
            int ch = mf * 16 + lg * 4 + r;
            if (ch < 27) {
                float v = acc[mf][r] + (ch < 18 ? b_off[ch] : b_mask[ch - 18]);
                if (ch >= 18) v = 1.f / (1.f + __expf(-v));
                om[(((size_t)b * 27 + ch) << 14) + (y << 7) + px] = v;
            }
        }
}

// ---------------- fused deform-gather + main GEMM (32 px, 512 thr) ----------
// Phase 0: per-(k,px) params: 4 folded weights + 2 row-pair byte offsets.
// Phase 1: corners are a 2x2 adjacent block; NHWC makes each corner ROW PAIR
//   256 B contiguous -> one dword load per row pair (lanes 0-31 = left px,
//   32-63 = right px, 2 ch/lane), permlane32_swap distributes both halves.
// Phase 2: MFMA, wave = (mfrag, n-half).
__global__ __launch_bounds__(512, 6) void k_fused(const ushort_t* __restrict__ xtb,
        const float* __restrict__ om, const uint4* __restrict__ wpm,
        const float* __restrict__ bias, float* __restrict__ out) {
    __shared__ __align__(16) ushort_t sm[32 * 576];    // idx ^= (px&7)<<3
    __shared__ __align__(16) float prm[288 * 8];       // [k][px][8]
    int blk = blockIdx.x;
    int b = blk >> 9, rem = blk & 511;
    int y = rem >> 2, xs = (rem & 3) * 32;
    int t = threadIdx.x, lane = t & 63, w = t >> 6;
    const char* xbB = (const char*)xtb + ((size_t)b << 21);
    const float* omb = om + (((size_t)b * 27) << 14) + (y << 7) + xs;

    // ---- phase 0 ----
    if (t < 288) {
        int k = t >> 5, px = t & 31;            // coalesced over px
        int ki = k / 3, kj = k - ki * 3;
        int x = xs + px;
        float dy = omb[((2 * k) << 14) + px];
        float dx = omb[((2 * k + 1) << 14) + px];
        float m  = omb[((18 + k) << 14) + px];
        float sy = (float)(y - 1 + ki) + dy;
        float sx = (float)(x - 1 + kj) + dx;
        float fy = floorf(sy), fx = floorf(sx);
        float wy1 = sy - fy, wx1 = sx - fx;
        float wy0 = 1.f - wy1, wx0 = 1.f - wx1;
        int iy0 = (int)fy, ix0 = (int)fx;
        int iy1 = iy0 + 1, ix1 = ix0 + 1;
        bool vy0 = (iy0 >= 0) & (iy0 < HH);
        bool vy1 = (iy1 >= 0) & (iy1 < HH);
        // row selection (exclusive, no double count when clamping collides)
        float wyr0 = vy0 ? wy0 : (vy1 ? wy1 : 0.f);
        int   ry0  = vy0 ? iy0 : (vy1 ? iy1 : 0);
        float wyr1 = (vy0 & vy1) ? wy1 : 0.f;
        int   ry1  = min(max(iy1, 0), HH - 1);
        // column pair: base bx covers pixels bx, bx+1 (provably exclusive)
        int bx = min(max(ix0, 0), WW - 2);
        float wxh0 = (bx == ix0) ? wx0 : ((bx == ix1) ? wx1 : 0.f);
        float wxh1 = (bx + 1 == ix1) ? wx1 : ((bx + 1 == ix0) ? wx0 : 0.f);
        float* pp = prm + t * 8;
        pp[0] = m * wyr0 * wxh0;
        pp[1] = m * wyr0 * wxh1;
        pp[2] = m * wyr1 * wxh0;
        pp[3] = m * wyr1 * wxh1;
        pp[4] = __uint_as_float((uint_t)(((ry0 << 7) + bx) << 7));   // byte off
        pp[5] = __uint_as_float((uint_t)(((ry1 << 7) + bx) << 7));
    }
    __syncthreads();

    // ---- phase 1: gather (wave = 4 px, 2 loads + 2 swaps per sample) ----
    {
        const int lane4 = lane << 2;
        bool wlo = lane < 32;
#pragma unroll
        for (int p = 0; p < 4; ++p) {
            int px = w * 4 + p;
#pragma unroll
            for (int k = 0; k < 9; ++k) {
                const float* pp = prm + ((k << 5) + px) * 8;
                f32x4 wv = *(const f32x4*)pp;
                uint_t a0 = __float_as_uint(pp[4]);
                uint_t a1 = __float_as_uint(pp[5]);
                uint_t vt = *(const uint_t*)(xbB + a0 + lane4);
                uint_t vb = *(const uint_t*)(xbB + a1 + lane4);
                v2i_t rt = __builtin_amdgcn_permlane32_swap((int)vt, (int)vt, false, false);
                v2i_t rb = __builtin_amdgcn_permlane32_swap((int)vb, (int)vb, false, false);
                // lanes<32: rt[0]=left-px val (own), rt[1]=right-px val
                float s0 = wv.x * blo(rt[0]) + wv.y * blo(rt[1])
                         + wv.z * blo(rb[0]) + wv.w * blo(rb[1]);
                float s1 = wv.x * bhi(rt[0]) + wv.y * bhi(rt[1])
                         + wv.z * bhi(rb[0]) + wv.w * bhi(rb[1]);
                if (wlo) {
                    uint_t pk2 = (uint_t)f2bf(s0) | ((uint_t)f2bf(s1) << 16);
                    int idx = (px * 576 + (k << 6) + (lane << 1)) ^ ((px & 7) << 3);
                    *(uint_t*)&sm[idx] = pk2;
                }
            }
        }
    }
    __syncthreads();

    // ---- phase 2: out[64 x 32] = W(64x576) . sm(576x32), 8 waves ----
    int lm = lane & 15, lg = lane >> 4;
    int mf = w & 3, nh = w >> 2;
    int px_r = (nh << 4) + lm;
    int sw = (px_r & 7) << 3;
    f32x4 acc = {};
#pragma unroll
    for (int ks = 0; ks < 18; ++ks) {
        short8 af = bc8(wpm[((ks << 2) + mf) * 64 + lane]);
        int bidx = (px_r * 576 + (ks << 5) + (lg << 3)) ^ sw;
        short8 bf = *(const short8*)&sm[bidx];
        acc = __builtin_amdgcn_mfma_f32_16x16x32_bf16(af, bf, acc, 0, 0, 0);
    }
#pragma unroll
    for (int r = 0; r < 4; ++r) {
        int o = (mf << 4) + (lg << 2) + r;
        out[(((size_t)b * 64 + o) << 14) + (y << 7) + xs + px_r] = acc[r] + bias[o];
    }
}

extern "C" void kernel_launch(void* const* d_in, const int* in_sizes, int n_in,
                              void* d_out, int out_size, void* d_ws, size_t ws_size,
                              hipStream_t stream) {
    const float* x      = (const float*)d_in[0];
    const float* w_off  = (const float*)d_in[1];
    const float* b_off  = (const float*)d_in[2];
    const float* w_mask = (const float*)d_in[3];
    const float* b_mask = (const float*)d_in[4];
    const float* w      = (const float*)d_in[5];
    const float* bias   = (const float*)d_in[6];
    float* out = (float*)d_out;

    char* ws = (char*)d_ws;
    ushort_t* xtb  = (ushort_t*)(ws);                    //  8,388,608 B
    float*    om   = (float*)(ws + 8388608);             //  7,077,888 B
    ushort_t* wpom = (ushort_t*)(ws + 15466496);         //     36,864 B
    ushort_t* wpm  = (ushort_t*)(ws + 15503360);         //     73,728 B

    hipLaunchKernelGGL(k_pack, dim3(216), dim3(256), 0, stream,
                       w_off, w_mask, w, wpom, wpm);
    hipLaunchKernelGGL(k_transpose_x, dim3(1024), dim3(256), 0, stream, x, xtb);
    hipLaunchKernelGGL(k_conv_om, dim3(512), dim3(512), 0, stream,
                       xtb, (const uint4*)wpom, b_off, b_mask, om);
    hipLaunchKernelGGL(k_fused, dim3(2048), dim3(512), 0, stream,
                       xtb, om, (const uint4*)wpm, bias, out);
}

// Round 5
// 59.268 us; speedup vs baseline: 1.3679x; 1.3679x over previous
//
#include <hip/hip_runtime.h>
#include <math.h>

typedef __attribute__((ext_vector_type(8))) short short8;
typedef __attribute__((ext_vector_type(4))) float f32x4;
typedef unsigned short ushort_t;
typedef unsigned int uint_t;

#define HH 128
#define WW 128
#define CC 64
#define HWp 16384

__device__ inline ushort_t f2bf(float f) {
    uint_t u = __float_as_uint(f);
    uint_t r = (u + 0x7FFFu + ((u >> 16) & 1u)) >> 16;
    return (ushort_t)r;
}
__device__ inline float blo(uint_t u) { return __uint_as_float(u << 16); }
__device__ inline float bhi(uint_t u) { return __uint_as_float(u & 0xFFFF0000u); }
__device__ inline short8 bc8(uint4 v) { return __builtin_bit_cast(short8, v); }

// ---------------- weight packing into MFMA A-fragment order -----------------
__global__ __launch_bounds__(256) void k_pack(const float* __restrict__ w_off,
        const float* __restrict__ w_mask, const float* __restrict__ w,
        ushort_t* __restrict__ wpom, ushort_t* __restrict__ wpm) {
    int idx = blockIdx.x * 256 + threadIdx.x;
    if (idx < 18432) {
        int e = idx;
        int j = e & 7, l = (e >> 3) & 63, mf = (e >> 9) & 1, ks = e >> 10;
        int ch = mf * 16 + (l & 15);
        int k = ks * 32 + ((l >> 4) << 3) + j;
        int c = k & 63, kk = k >> 6;
        float v = 0.f;
        if (ch < 18) v = w_off[(ch * CC + c) * 9 + kk];
        else if (ch < 27) v = w_mask[((ch - 18) * CC + c) * 9 + kk];
        wpom[idx] = f2bf(v);
    } else if (idx < 18432 + 36864) {
        int e = idx - 18432;
        int j = e & 7, l = (e >> 3) & 63, mf = (e >> 9) & 3, ks = e >> 11;
        int o = mf * 16 + (l & 15);
        int k = ks * 32 + ((l >> 4) << 3) + j;
        int c = k & 63, kk = k >> 6;
        wpm[e] = f2bf(w[(o * CC + c) * 9 + kk]);
    }
}

// ---------------- x: NCHW f32 -> NHWC bf16 ----------------------------------
__global__ __launch_bounds__(256) void k_transpose_x(const float* __restrict__ x,
                                                     ushort_t* __restrict__ xtb) {
    __shared__ float tile[64][65];
    int bid = blockIdx.x;
    int xs = (bid & 1) * 64;
    int y  = (bid >> 1) & 127;
    int b  = bid >> 8;
    int t = threadIdx.x, lane = t & 63, g = t >> 6;
#pragma unroll
    for (int i = 0; i < 16; ++i) {
        int c = i * 4 + g;
        tile[c][lane] = x[(((size_t)b * CC + c) * HH + y) * WW + xs + lane];
    }
    __syncthreads();
#pragma unroll
    for (int i = 0; i < 16; ++i) {
        int xx = i * 4 + g;
        xtb[(((size_t)b * HH + y) * WW + xs + xx) * CC + lane] = f2bf(tile[lane][xx]);
    }
}

// ---------------- offset/mask conv as MFMA GEMM (512 thr, 8 waves) ----------
__global__ __launch_bounds__(512, 4) void k_conv_om(const ushort_t* __restrict__ xtb,
        const uint4* __restrict__ wpom, const float* __restrict__ b_off,
        const float* __restrict__ b_mask, float* __restrict__ om) {
    __shared__ ushort_t xrow[3 * 132 * 64];   // idx ^= (col&7)<<3 swizzle
    int blk = blockIdx.x;
    int y = blk & 127, b = blk >> 7;
    int t = threadIdx.x;

    for (int ky = 0; ky < 3; ++ky) {
        int yy = y + ky - 1;
        bool ok = (yy >= 0) && (yy < HH);
#pragma unroll
        for (int i = 0; i < 2; ++i) {
            int t2 = i * 512 + t;
            int colr = t2 >> 3;
            int c0 = (t2 & 7) * 8;
            uint4 v = make_uint4(0u, 0u, 0u, 0u);
            if (ok) v = *(const uint4*)&xtb[(((size_t)b * HWp) + yy * WW + colr) * CC + c0];
            int col = colr + 1;
            int idx = ((ky * 132 + col) * 64 + c0) ^ ((col & 7) << 3);
            *(uint4*)&xrow[idx] = v;
        }
    }
    if (t < 48) {
        int ky = t >> 4, cs = (t >> 3) & 1, chn = t & 7;
        int col = cs ? 129 : 0;
        int idx = ((ky * 132 + col) * 64 + chn * 8) ^ ((col & 7) << 3);
        *(uint4*)&xrow[idx] = make_uint4(0u, 0u, 0u, 0u);
    }
    __syncthreads();

    int lane = t & 63, w = t >> 6;
    int lm = lane & 15, lg = lane >> 4;
    int px = w * 16 + lm;
    f32x4 acc[2] = {};
#pragma unroll
    for (int ks = 0; ks < 18; ++ks) {
        int kk = ks >> 1;
        int kyy = kk / 3, kxx = kk % 3;
        int c0 = (ks & 1) * 32 + lg * 8;
        short8 a0 = bc8(wpom[(ks * 2 + 0) * 64 + lane]);
        short8 a1 = bc8(wpom[(ks * 2 + 1) * 64 + lane]);
        int col = px + kxx;
        int idx = ((kyy * 132 + col) * 64 + c0) ^ ((col & 7) << 3);
        short8 bf = *(const short8*)&xrow[idx];
        acc[0] = __builtin_amdgcn_mfma_f32_16x16x32_bf16(a0, bf, acc[0], 0, 0, 0);
        acc[1] = __builtin_amdgcn_mfma_f32_16x16x32_bf16(a1, bf, acc[1], 0, 0, 0);
    }
#pragma unroll
    for (int mf = 0; mf < 2; ++mf)
#pragma unroll
        for (int r = 0; r < 4; ++r) {
            int ch = mf * 16 + lg * 4 + r;
            if (ch < 27) {
                float v = acc[mf][r] + (ch < 18 ? b_off[ch] : b_mask[ch - 18]);
                if (ch >= 18) v = 1.f / (1.f + __expf(-v));
                om[(((size_t)b * 27 + ch) << 14) + (y << 7) + px] = v;
            }
        }
}

// ---------------- fused deform-gather + main GEMM (32 px, 512 thr) ----------
// Phase 0: per-(k,px) params: 4 folded weights, 2 row-pair byte offsets,
//          LDS write base index + XOR swizzle (precomputed, no div in phase 1).
// Phase 1: 16-lane group = one sample; lane owns 4 channels via 4 x dwordx2
//          (right pixel at +128 imm). No duplicated math, no cross-lane ops.
// Phase 2: MFMA, wave = (mfrag, n-half).
__global__ __launch_bounds__(512, 4) void k_fused(const ushort_t* __restrict__ xtb,
        const float* __restrict__ om, const uint4* __restrict__ wpm,
        const float* __restrict__ bias, float* __restrict__ out) {
    __shared__ __align__(16) ushort_t sm[32 * 576];    // idx ^= ((px^k)&7)<<3
    __shared__ __align__(16) float prm[288 * 8];       // [s = px*9+k][8]
    int blk = blockIdx.x;
    int b = blk >> 9, rem = blk & 511;
    int y = rem >> 2, xs = (rem & 3) * 32;
    int t = threadIdx.x, lane = t & 63, w = t >> 6;
    const char* xbB = (const char*)xtb + ((size_t)b << 21);
    const float* omb = om + (((size_t)b * 27) << 14) + (y << 7) + xs;

    // ---- phase 0 (compute mapping t=[k][px] for coalesced om reads) ----
    if (t < 288) {
        int k = t >> 5, px = t & 31;
        int ki = k / 3, kj = k - ki * 3;
        int x = xs + px;
        float dy = omb[((2 * k) << 14) + px];
        float dx = omb[((2 * k + 1) << 14) + px];
        float m  = omb[((18 + k) << 14) + px];
        float sy = (float)(y - 1 + ki) + dy;
        float sx = (float)(x - 1 + kj) + dx;
        float fy = floorf(sy), fx = floorf(sx);
        float wy1 = sy - fy, wx1 = sx - fx;
        float wy0 = 1.f - wy1, wx0 = 1.f - wx1;
        int iy0 = (int)fy, ix0 = (int)fx;
        int iy1 = iy0 + 1, ix1 = ix0 + 1;
        bool vy0 = (iy0 >= 0) & (iy0 < HH);
        bool vy1 = (iy1 >= 0) & (iy1 < HH);
        float wyr0 = vy0 ? wy0 : (vy1 ? wy1 : 0.f);
        int   ry0  = vy0 ? iy0 : (vy1 ? iy1 : 0);
        float wyr1 = (vy0 & vy1) ? wy1 : 0.f;
        int   ry1  = min(max(iy1, 0), HH - 1);
        int bx = min(max(ix0, 0), WW - 2);
        float wxh0 = (bx == ix0) ? wx0 : ((bx == ix1) ? wx1 : 0.f);
        float wxh1 = (bx + 1 == ix1) ? wx1 : ((bx + 1 == ix0) ? wx0 : 0.f);
        int s = px * 9 + k;
        float* pp = prm + s * 8;
        pp[0] = m * wyr0 * wxh0;
        pp[1] = m * wyr0 * wxh1;
        pp[2] = m * wyr1 * wxh0;
        pp[3] = m * wyr1 * wxh1;
        pp[4] = __uint_as_float((uint_t)(((ry0 << 7) + bx) << 7));   // top byte off
        pp[5] = __uint_as_float((uint_t)(((ry1 << 7) + bx) << 7));   // bot byte off
        pp[6] = __uint_as_float((uint_t)(px * 576 + k * 64));        // sm ushort base
        pp[7] = __uint_as_float((uint_t)(((px ^ k) & 7) << 3));      // swizzle
    }
    __syncthreads();

    // ---- phase 1: gather (16-lane group = 1 sample, 4 ch/lane) ----
    {
        int g = lane & 15;
        int q = lane >> 4;
        int sbase = w * 36 + q;
        int g8 = g << 3;
#pragma unroll
        for (int i = 0; i < 9; ++i) {
            int s = sbase + i * 4;
            const float* pp = prm + s * 8;
            f32x4 wv  = *(const f32x4*)pp;
            f32x4 aux = *(const f32x4*)(pp + 4);
            uint_t aT = __float_as_uint(aux.x) + (uint_t)g8;
            uint_t aB = __float_as_uint(aux.y) + (uint_t)g8;
            uint2 tl = *(const uint2*)(xbB + aT);
            uint2 tr = *(const uint2*)(xbB + aT + 128);
            uint2 bl = *(const uint2*)(xbB + aB);
            uint2 br = *(const uint2*)(xbB + aB + 128);
            float s0 = wv.x*blo(tl.x) + wv.y*blo(tr.x) + wv.z*blo(bl.x) + wv.w*blo(br.x);
            float s1 = wv.x*bhi(tl.x) + wv.y*bhi(tr.x) + wv.z*bhi(bl.x) + wv.w*bhi(br.x);
            float s2 = wv.x*blo(tl.y) + wv.y*blo(tr.y) + wv.z*blo(bl.y) + wv.w*blo(br.y);
            float s3 = wv.x*bhi(tl.y) + wv.y*bhi(tr.y) + wv.z*bhi(bl.y) + wv.w*bhi(br.y);
            uint_t r01, r23;
            asm("v_cvt_pk_bf16_f32 %0, %1, %2" : "=v"(r01) : "v"(s0), "v"(s1));
            asm("v_cvt_pk_bf16_f32 %0, %1, %2" : "=v"(r23) : "v"(s2), "v"(s3));
            int widx = (int)((__float_as_uint(aux.z) + (uint_t)(g << 2)) ^ __float_as_uint(aux.w));
            *(uint2*)&sm[widx] = make_uint2(r01, r23);
        }
    }
    __syncthreads();

    // ---- phase 2: out[64 x 32] = W(64x576) . sm(576x32), 8 waves ----
    int lm = lane & 15, lg = lane >> 4;
    int mf = w & 3, nh = w >> 2;
    int px_r = (nh << 4) + lm;
    f32x4 acc = {};
#pragma unroll
    for (int ks = 0; ks < 18; ++ks) {
        short8 af = bc8(wpm[((ks << 2) + mf) * 64 + lane]);
        int bidx = (px_r * 576 + (ks << 5) + (lg << 3)) ^ (((px_r ^ (ks >> 1)) & 7) << 3);
        short8 bf = *(const short8*)&sm[bidx];
        acc = __builtin_amdgcn_mfma_f32_16x16x32_bf16(af, bf, acc, 0, 0, 0);
    }
#pragma unroll
    for (int r = 0; r < 4; ++r) {
        int o = (mf << 4) + (lg << 2) + r;
        out[(((size_t)b * 64 + o) << 14) + (y << 7) + xs + px_r] = acc[r] + bias[o];
    }
}

extern "C" void kernel_launch(void* const* d_in, const int* in_sizes, int n_in,
                              void* d_out, int out_size, void* d_ws, size_t ws_size,
                              hipStream_t stream) {
    const float* x      = (const float*)d_in[0];
    const float* w_off  = (const float*)d_in[1];
    const float* b_off  = (const float*)d_in[2];
    const float* w_mask = (const float*)d_in[3];
    const float* b_mask = (const float*)d_in[4];
    const float* w      = (const float*)d_in[5];
    const float* bias   = (const float*)d_in[6];
    float* out = (float*)d_out;

    char* ws = (char*)d_ws;
    ushort_t* xtb  = (ushort_t*)(ws);                    //  8,388,608 B
    float*    om   = (float*)(ws + 8388608);             //  7,077,888 B
    ushort_t* wpom = (ushort_t*)(ws + 15466496);         //     36,864 B
    ushort_t* wpm  = (ushort_t*)(ws + 15503360);         //     73,728 B

    hipLaunchKernelGGL(k_pack, dim3(216), dim3(256), 0, stream,
                       w_off, w_mask, w, wpom, wpm);
    hipLaunchKernelGGL(k_transpose_x, dim3(1024), dim3(256), 0, stream, x, xtb);
    hipLaunchKernelGGL(k_conv_om, dim3(512), dim3(512), 0, stream,
                       xtb, (const uint4*)wpom, b_off, b_mask, om);
    hipLaunchKernelGGL(k_fused, dim3(2048), dim3(512), 0, stream,
                       xtb, om, (const uint4*)wpm, bias, out);
}